// Round 1
// baseline (36.033 us; speedup 1.0000x reference)
//
#include <hip/hip_runtime.h>

#define NT 128   // threads per block = samples per block
#define NJ 22

struct X9 { float r[9]; float t[3]; };

__device__ __forceinline__ void rodrigues(float ax, float ay, float az, float* R) {
    // matches reference: sq = |aa|^2; angle = sqrt(sq + 1e-12); axis = aa/angle
    float sq   = ax*ax + ay*ay + az*az + 1e-12f;
    float rinv = rsqrtf(sq);
    float ang  = sq * rinv;          // sqrt(sq)
    float s, c;
    __sincosf(ang, &s, &c);
    float x = ax*rinv, y = ay*rinv, z = az*rinv;
    float t = 1.0f - c;
    R[0] = t*x*x + c;   R[1] = t*x*y - s*z; R[2] = t*x*z + s*y;
    R[3] = t*x*y + s*z; R[4] = t*y*y + c;   R[5] = t*y*z - s*x;
    R[6] = t*x*z - s*y; R[7] = t*y*z + s*x; R[8] = t*z*z + c;
}

// local[j] = LT[j] + sum_k betas[k]*LD[j][k]   (parent diff pre-folded into tables)
__device__ __forceinline__ void local_pos(int j, const float* bt,
                                          const float* LT, const float* LD,
                                          float* lt) {
    #pragma unroll
    for (int c = 0; c < 3; ++c) {
        float v = LT[j*3 + c];
        #pragma unroll
        for (int k = 0; k < 10; ++k)
            v = fmaf(bt[k], LD[(j*3 + c)*10 + k], v);
        lt[c] = v;
    }
}

template<int J>
__device__ __forceinline__ X9 step(const X9& gp, const float* bp, const float* bt,
                                   const float* LT, const float* LD, float* outp) {
    float R[9];
    rodrigues(bp[(J-1)*3 + 0], bp[(J-1)*3 + 1], bp[(J-1)*3 + 2], R);
    float lt[3];
    local_pos(J, bt, LT, LD, lt);
    X9 g;
    #pragma unroll
    for (int r = 0; r < 3; ++r) {
        #pragma unroll
        for (int c = 0; c < 3; ++c)
            g.r[r*3+c] = fmaf(gp.r[r*3+0], R[c],
                         fmaf(gp.r[r*3+1], R[3+c],
                              gp.r[r*3+2] * R[6+c]));
        g.t[r] = fmaf(gp.r[r*3+0], lt[0],
                 fmaf(gp.r[r*3+1], lt[1],
                 fmaf(gp.r[r*3+2], lt[2], gp.t[r])));
    }
    outp[J*3+0] = g.t[0]; outp[J*3+1] = g.t[1]; outp[J*3+2] = g.t[2];
    return g;
}

__global__ __launch_bounds__(NT) void fk_joints_kernel(
    const float* __restrict__ body_pose,     // (S,63)
    const float* __restrict__ betas,         // (S,10)
    const float* __restrict__ global_orient, // (S,3)
    const float* __restrict__ transl,        // (S,3)
    const float* __restrict__ J_template,    // (22,3)
    const float* __restrict__ J_shapedirs,   // (22,3,10)
    float* __restrict__ out)                 // (S,22,3)
{
    __shared__ float s_bp[NT*63];
    __shared__ float s_bt[NT*10];
    __shared__ float s_go[NT*3];
    __shared__ float s_tr[NT*3];
    __shared__ float s_LT[NJ*3];
    __shared__ float s_LD[NJ*3*10];

    const int tid = threadIdx.x;
    const long long s0 = (long long)blockIdx.x * NT;

    // ---- coalesced float4 staging of per-sample inputs ----
    {
        const float4* src = reinterpret_cast<const float4*>(body_pose + s0*63);
        float4* dst = reinterpret_cast<float4*>(s_bp);
        #pragma unroll 4
        for (int i = tid; i < NT*63/4; i += NT) dst[i] = src[i];
    }
    {
        const float4* src = reinterpret_cast<const float4*>(betas + s0*10);
        float4* dst = reinterpret_cast<float4*>(s_bt);
        for (int i = tid; i < NT*10/4; i += NT) dst[i] = src[i];
    }
    {
        const float4* src = reinterpret_cast<const float4*>(global_orient + s0*3);
        float4* dst = reinterpret_cast<float4*>(s_go);
        if (tid < NT*3/4) dst[tid] = src[tid];
    }
    {
        const float4* src = reinterpret_cast<const float4*>(transl + s0*3);
        float4* dst = reinterpret_cast<float4*>(s_tr);
        if (tid < NT*3/4) dst[tid] = src[tid];
    }

    // ---- parent-difference tables (once per block) ----
    const int P[NJ] = {0,0,0,0,1,2,3,4,5,6,7,8,9,9,9,12,13,14,16,17,18,19};
    for (int i = tid; i < NJ*3; i += NT) {
        int j = i/3, c = i - j*3;
        float v = J_template[i];
        if (j) v -= J_template[P[j]*3 + c];   // j==0: local = skeleton[0] (+transl later)
        s_LT[i] = v;
    }
    for (int i = tid; i < NJ*30; i += NT) {
        int jc = i/10, k = i - jc*10;
        int j = jc/3,  c = jc - j*3;
        float v = J_shapedirs[i];
        if (j) v -= J_shapedirs[(P[j]*3 + c)*10 + k];
        s_LD[i] = v;
    }
    __syncthreads();

    // ---- per-thread FK ----
    float bt[10];
    #pragma unroll
    for (int k = 0; k < 10; ++k) bt[k] = s_bt[tid*10 + k];

    const float* bp = &s_bp[tid*63];
    float* outp = out + (s0 + tid) * (NJ*3);

    // root (joint 0): G0.R = R0, G0.t = skeleton[0] + transl
    X9 g0;
    rodrigues(s_go[tid*3+0], s_go[tid*3+1], s_go[tid*3+2], g0.r);
    {
        float lt0[3];
        local_pos(0, bt, s_LT, s_LD, lt0);
        g0.t[0] = lt0[0] + s_tr[tid*3+0];
        g0.t[1] = lt0[1] + s_tr[tid*3+1];
        g0.t[2] = lt0[2] + s_tr[tid*3+2];
        outp[0] = g0.t[0]; outp[1] = g0.t[1]; outp[2] = g0.t[2];
    }

    X9 g;
    // chain A: 0 -> 1 -> 4 -> 7 -> 10
    g = step<1 >(g0, bp, bt, s_LT, s_LD, outp);
    g = step<4 >(g,  bp, bt, s_LT, s_LD, outp);
    g = step<7 >(g,  bp, bt, s_LT, s_LD, outp);
    g = step<10>(g,  bp, bt, s_LT, s_LD, outp);
    // chain B: 0 -> 2 -> 5 -> 8 -> 11
    g = step<2 >(g0, bp, bt, s_LT, s_LD, outp);
    g = step<5 >(g,  bp, bt, s_LT, s_LD, outp);
    g = step<8 >(g,  bp, bt, s_LT, s_LD, outp);
    g = step<11>(g,  bp, bt, s_LT, s_LD, outp);
    // chain C: 0 -> 3 -> 6 -> 9 (save g9)
    g = step<3 >(g0, bp, bt, s_LT, s_LD, outp);
    g = step<6 >(g,  bp, bt, s_LT, s_LD, outp);
    X9 g9 = step<9>(g, bp, bt, s_LT, s_LD, outp);
    // chain D: 9 -> 12 -> 15
    g = step<12>(g9, bp, bt, s_LT, s_LD, outp);
    g = step<15>(g,  bp, bt, s_LT, s_LD, outp);
    // chain E: 9 -> 13 -> 16 -> 18 -> 20
    g = step<13>(g9, bp, bt, s_LT, s_LD, outp);
    g = step<16>(g,  bp, bt, s_LT, s_LD, outp);
    g = step<18>(g,  bp, bt, s_LT, s_LD, outp);
    g = step<20>(g,  bp, bt, s_LT, s_LD, outp);
    // chain F: 9 -> 14 -> 17 -> 19 -> 21
    g = step<14>(g9, bp, bt, s_LT, s_LD, outp);
    g = step<17>(g,  bp, bt, s_LT, s_LD, outp);
    g = step<19>(g,  bp, bt, s_LT, s_LD, outp);
    g = step<21>(g,  bp, bt, s_LT, s_LD, outp);
}

extern "C" void kernel_launch(void* const* d_in, const int* in_sizes, int n_in,
                              void* d_out, int out_size, void* d_ws, size_t ws_size,
                              hipStream_t stream) {
    const float* body_pose     = (const float*)d_in[0];
    const float* betas         = (const float*)d_in[1];
    const float* global_orient = (const float*)d_in[2];
    const float* transl        = (const float*)d_in[3];
    const float* J_template    = (const float*)d_in[4];
    const float* J_shapedirs   = (const float*)d_in[5];
    float* out = (float*)d_out;

    const int S = in_sizes[0] / 63;        // B*L = 131072 (divisible by NT)
    const int blocks = S / NT;

    hipLaunchKernelGGL(fk_joints_kernel, dim3(blocks), dim3(NT), 0, stream,
                       body_pose, betas, global_orient, transl,
                       J_template, J_shapedirs, out);
}

// Round 2
// 35.684 us; speedup vs baseline: 1.0098x; 1.0098x over previous
//
#include <hip/hip_runtime.h>

#define NT 128   // threads per block = samples per block
#define NJ 22

struct X9 { float r[9]; float t[3]; };

__device__ __forceinline__ void rodrigues(float ax, float ay, float az, float* R) {
    float sq   = ax*ax + ay*ay + az*az + 1e-12f;
    float rinv = rsqrtf(sq);
    float ang  = sq * rinv;          // sqrt(sq)
    float s, c;
    __sincosf(ang, &s, &c);
    float x = ax*rinv, y = ay*rinv, z = az*rinv;
    float t = 1.0f - c;
    R[0] = t*x*x + c;   R[1] = t*x*y - s*z; R[2] = t*x*z + s*y;
    R[3] = t*x*y + s*z; R[4] = t*y*y + c;   R[5] = t*y*z - s*x;
    R[6] = t*x*z - s*y; R[7] = t*y*z + s*x; R[8] = t*z*z + c;
}

// local[j] = LT[j] + sum_k betas[k]*LDpad[j][k], rows padded to 12 floats (3x float4)
__device__ __forceinline__ void local_pos(int j, const float* bt,
                                          const float* LT, const float4* LD4,
                                          float* lt) {
    #pragma unroll
    for (int c = 0; c < 3; ++c) {
        float v = LT[j*3 + c];
        const float4 a0 = LD4[(j*3 + c)*3 + 0];
        const float4 a1 = LD4[(j*3 + c)*3 + 1];
        const float4 a2 = LD4[(j*3 + c)*3 + 2];
        v = fmaf(bt[0], a0.x, v); v = fmaf(bt[1], a0.y, v);
        v = fmaf(bt[2], a0.z, v); v = fmaf(bt[3], a0.w, v);
        v = fmaf(bt[4], a1.x, v); v = fmaf(bt[5], a1.y, v);
        v = fmaf(bt[6], a1.z, v); v = fmaf(bt[7], a1.w, v);
        v = fmaf(bt[8], a2.x, v); v = fmaf(bt[9], a2.y, v);
        lt[c] = v;   // pad lanes a2.z/a2.w are zero anyway; skip 2 FMAs
    }
}

// consumes bp[(J-1)*3..+2], writes g.t back into the SAME slots (in-place reuse)
template<int J>
__device__ __forceinline__ X9 step(const X9& gp, float* bp, const float* bt,
                                   const float* LT, const float4* LD4) {
    float R[9];
    rodrigues(bp[(J-1)*3 + 0], bp[(J-1)*3 + 1], bp[(J-1)*3 + 2], R);
    float lt[3];
    local_pos(J, bt, LT, LD4, lt);
    X9 g;
    #pragma unroll
    for (int r = 0; r < 3; ++r) {
        #pragma unroll
        for (int c = 0; c < 3; ++c)
            g.r[r*3+c] = fmaf(gp.r[r*3+0], R[c],
                         fmaf(gp.r[r*3+1], R[3+c],
                              gp.r[r*3+2] * R[6+c]));
        g.t[r] = fmaf(gp.r[r*3+0], lt[0],
                 fmaf(gp.r[r*3+1], lt[1],
                 fmaf(gp.r[r*3+2], lt[2], gp.t[r])));
    }
    bp[(J-1)*3+0] = g.t[0]; bp[(J-1)*3+1] = g.t[1]; bp[(J-1)*3+2] = g.t[2];
    return g;
}

__global__ __launch_bounds__(NT) void fk_joints_kernel(
    const float* __restrict__ body_pose,     // (S,63)
    const float* __restrict__ betas,         // (S,10)
    const float* __restrict__ global_orient, // (S,3)
    const float* __restrict__ transl,        // (S,3)
    const float* __restrict__ J_template,    // (22,3)
    const float* __restrict__ J_shapedirs,   // (22,3,10)
    float* __restrict__ out)                 // (S,22,3)
{
    __shared__ float  s_bp[NT*63];
    __shared__ float  s_bt[NT*10];
    __shared__ float  s_go[NT*3];
    __shared__ float  s_tr[NT*3];
    __shared__ float  s_LT[NJ*3];
    __shared__ float4 s_LD4[NJ*3*3];   // 66 rows x 12 floats (2 pad)

    const int tid = threadIdx.x;
    const long long s0 = (long long)blockIdx.x * NT;

    // ---- coalesced float4 staging of per-sample inputs ----
    {
        const float4* src = reinterpret_cast<const float4*>(body_pose + s0*63);
        float4* dst = reinterpret_cast<float4*>(s_bp);
        #pragma unroll 4
        for (int i = tid; i < NT*63/4; i += NT) dst[i] = src[i];
    }
    {
        const float4* src = reinterpret_cast<const float4*>(betas + s0*10);
        float4* dst = reinterpret_cast<float4*>(s_bt);
        for (int i = tid; i < NT*10/4; i += NT) dst[i] = src[i];
    }
    {
        const float4* src = reinterpret_cast<const float4*>(global_orient + s0*3);
        float4* dst = reinterpret_cast<float4*>(s_go);
        if (tid < NT*3/4) dst[tid] = src[tid];
    }
    {
        const float4* src = reinterpret_cast<const float4*>(transl + s0*3);
        float4* dst = reinterpret_cast<float4*>(s_tr);
        if (tid < NT*3/4) dst[tid] = src[tid];
    }

    // ---- parent-difference tables (once per block), LD padded to 12/row ----
    const int P[NJ] = {0,0,0,0,1,2,3,4,5,6,7,8,9,9,9,12,13,14,16,17,18,19};
    float* s_LD = reinterpret_cast<float*>(s_LD4);
    for (int i = tid; i < NJ*3; i += NT) {
        int j = i/3, c = i - j*3;
        float v = J_template[i];
        if (j) v -= J_template[P[j]*3 + c];
        s_LT[i] = v;
        s_LD[i*12 + 10] = 0.0f;  // pads
        s_LD[i*12 + 11] = 0.0f;
    }
    for (int i = tid; i < NJ*30; i += NT) {
        int jc = i/10, k = i - jc*10;
        int j = jc/3,  c = jc - j*3;
        float v = J_shapedirs[i];
        if (j) v -= J_shapedirs[(P[j]*3 + c)*10 + k];
        s_LD[jc*12 + k] = v;
    }
    __syncthreads();

    // ---- per-thread FK ----
    float bt[10];
    #pragma unroll
    for (int k = 0; k < 10; ++k) bt[k] = s_bt[tid*10 + k];

    float* bp = &s_bp[tid*63];

    // root (joint 0): G0.R = R0, G0.t = skeleton[0] + transl -> stored into s_go slot
    X9 g0;
    rodrigues(s_go[tid*3+0], s_go[tid*3+1], s_go[tid*3+2], g0.r);
    {
        float lt0[3];
        local_pos(0, bt, s_LT, s_LD4, lt0);
        g0.t[0] = lt0[0] + s_tr[tid*3+0];
        g0.t[1] = lt0[1] + s_tr[tid*3+1];
        g0.t[2] = lt0[2] + s_tr[tid*3+2];
        s_go[tid*3+0] = g0.t[0]; s_go[tid*3+1] = g0.t[1]; s_go[tid*3+2] = g0.t[2];
    }

    X9 g;
    // chain A: 0 -> 1 -> 4 -> 7 -> 10
    g = step<1 >(g0, bp, bt, s_LT, s_LD4);
    g = step<4 >(g,  bp, bt, s_LT, s_LD4);
    g = step<7 >(g,  bp, bt, s_LT, s_LD4);
    g = step<10>(g,  bp, bt, s_LT, s_LD4);
    // chain B: 0 -> 2 -> 5 -> 8 -> 11
    g = step<2 >(g0, bp, bt, s_LT, s_LD4);
    g = step<5 >(g,  bp, bt, s_LT, s_LD4);
    g = step<8 >(g,  bp, bt, s_LT, s_LD4);
    g = step<11>(g,  bp, bt, s_LT, s_LD4);
    // chain C: 0 -> 3 -> 6 -> 9 (save g9)
    g = step<3 >(g0, bp, bt, s_LT, s_LD4);
    g = step<6 >(g,  bp, bt, s_LT, s_LD4);
    X9 g9 = step<9>(g, bp, bt, s_LT, s_LD4);
    // chain D: 9 -> 12 -> 15
    g = step<12>(g9, bp, bt, s_LT, s_LD4);
    g = step<15>(g,  bp, bt, s_LT, s_LD4);
    // chain E: 9 -> 13 -> 16 -> 18 -> 20
    g = step<13>(g9, bp, bt, s_LT, s_LD4);
    g = step<16>(g,  bp, bt, s_LT, s_LD4);
    g = step<18>(g,  bp, bt, s_LT, s_LD4);
    g = step<20>(g,  bp, bt, s_LT, s_LD4);
    // chain F: 9 -> 14 -> 17 -> 19 -> 21
    g = step<14>(g9, bp, bt, s_LT, s_LD4);
    g = step<17>(g,  bp, bt, s_LT, s_LD4);
    g = step<19>(g,  bp, bt, s_LT, s_LD4);
    g = step<21>(g,  bp, bt, s_LT, s_LD4);

    __syncthreads();

    // ---- coalesced float4 output: gather from s_go (joint 0) / s_bp (joints 1..21) ----
    {
        float4* dst = reinterpret_cast<float4*>(out + s0 * (NJ*3));
        const int TOT4 = NT*NJ*3/4;   // 2112
        for (int i = tid; i < TOT4; i += NT) {
            const int f0 = i*4;
            float v[4];
            #pragma unroll
            for (int q = 0; q < 4; ++q) {
                int f = f0 + q;
                int s = f / 66;
                int r = f - s*66;            // r = j*3 + c
                v[q] = (r < 3) ? s_go[s*3 + r] : s_bp[s*63 + (r - 3)];
            }
            dst[i] = make_float4(v[0], v[1], v[2], v[3]);
        }
    }
}

extern "C" void kernel_launch(void* const* d_in, const int* in_sizes, int n_in,
                              void* d_out, int out_size, void* d_ws, size_t ws_size,
                              hipStream_t stream) {
    const float* body_pose     = (const float*)d_in[0];
    const float* betas         = (const float*)d_in[1];
    const float* global_orient = (const float*)d_in[2];
    const float* transl        = (const float*)d_in[3];
    const float* J_template    = (const float*)d_in[4];
    const float* J_shapedirs   = (const float*)d_in[5];
    float* out = (float*)d_out;

    const int S = in_sizes[0] / 63;        // B*L = 131072 (divisible by NT)
    const int blocks = S / NT;

    hipLaunchKernelGGL(fk_joints_kernel, dim3(blocks), dim3(NT), 0, stream,
                       body_pose, betas, global_orient, transl,
                       J_template, J_shapedirs, out);
}

// Round 3
// 29.297 us; speedup vs baseline: 1.2299x; 1.2180x over previous
//
#include <hip/hip_runtime.h>

#define NT 128   // threads per block = samples per block
#define NJ 22

struct X9 { float r[9]; float t[3]; };

__device__ __forceinline__ void rodrigues(float ax, float ay, float az, float* R) {
    float sq   = ax*ax + ay*ay + az*az + 1e-12f;
    float rinv = rsqrtf(sq);
    float ang  = sq * rinv;          // sqrt(sq)
    float s, c;
    __sincosf(ang, &s, &c);
    float x = ax*rinv, y = ay*rinv, z = az*rinv;
    float t = 1.0f - c;
    R[0] = t*x*x + c;   R[1] = t*x*y - s*z; R[2] = t*x*z + s*y;
    R[3] = t*x*y + s*z; R[4] = t*y*y + c;   R[5] = t*y*z - s*x;
    R[6] = t*x*z - s*y; R[7] = t*y*z + s*x; R[8] = t*z*z + c;
}

// local[j] = LT[j] + sum_k betas[k]*LDpad[j][k], rows padded to 12 floats (3x float4)
__device__ __forceinline__ void local_pos(int j, const float* bt,
                                          const float* LT, const float4* LD4,
                                          float* lt) {
    #pragma unroll
    for (int c = 0; c < 3; ++c) {
        float v = LT[j*3 + c];
        const float4 a0 = LD4[(j*3 + c)*3 + 0];
        const float4 a1 = LD4[(j*3 + c)*3 + 1];
        const float4 a2 = LD4[(j*3 + c)*3 + 2];
        v = fmaf(bt[0], a0.x, v); v = fmaf(bt[1], a0.y, v);
        v = fmaf(bt[2], a0.z, v); v = fmaf(bt[3], a0.w, v);
        v = fmaf(bt[4], a1.x, v); v = fmaf(bt[5], a1.y, v);
        v = fmaf(bt[6], a1.z, v); v = fmaf(bt[7], a1.w, v);
        v = fmaf(bt[8], a2.x, v); v = fmaf(bt[9], a2.y, v);
        lt[c] = v;
    }
}

// aa: 63 axis-angle floats in REGISTERS (compile-time indexed). Output t -> LDS s_o.
template<int J>
__device__ __forceinline__ X9 step(const X9& gp, const float* aa, const float* bt,
                                   const float* LT, const float4* LD4, float* s_o) {
    float R[9];
    rodrigues(aa[(J-1)*3 + 0], aa[(J-1)*3 + 1], aa[(J-1)*3 + 2], R);
    float lt[3];
    local_pos(J, bt, LT, LD4, lt);
    X9 g;
    #pragma unroll
    for (int r = 0; r < 3; ++r) {
        #pragma unroll
        for (int c = 0; c < 3; ++c)
            g.r[r*3+c] = fmaf(gp.r[r*3+0], R[c],
                         fmaf(gp.r[r*3+1], R[3+c],
                              gp.r[r*3+2] * R[6+c]));
        g.t[r] = fmaf(gp.r[r*3+0], lt[0],
                 fmaf(gp.r[r*3+1], lt[1],
                 fmaf(gp.r[r*3+2], lt[2], gp.t[r])));
    }
    s_o[J*3+0] = g.t[0]; s_o[J*3+1] = g.t[1]; s_o[J*3+2] = g.t[2];
    return g;
}

__global__ __launch_bounds__(NT, 2) void fk_joints_kernel(
    const float* __restrict__ body_pose,     // (S,63)
    const float* __restrict__ betas,         // (S,10)
    const float* __restrict__ global_orient, // (S,3)
    const float* __restrict__ transl,        // (S,3)
    const float* __restrict__ J_template,    // (22,3)
    const float* __restrict__ J_shapedirs,   // (22,3,10)
    float* __restrict__ out)                 // (S,22,3)
{
    // ONE time-shared buffer: bp staging -> betas/go/tr staging -> output gather.
    // 33792B + tables ~3.4KB = ~37.2KB -> 4 blocks/CU -> 8 waves/CU (structural max).
    __shared__ float  s_buf[NT*66];          // 8448 floats
    __shared__ float  s_LT[NJ*3];
    __shared__ float4 s_LD4[NJ*3*3];         // 66 rows x 12 floats (2 pad)

    const int tid = threadIdx.x;
    const long long s0 = (long long)blockIdx.x * NT;

    // ---- phase 1: stage body_pose (2016 float4) + build tables ----
    {
        const float4* src = reinterpret_cast<const float4*>(body_pose + s0*63);
        float4* dst = reinterpret_cast<float4*>(s_buf);
        for (int i = tid; i < NT*63/4; i += NT) dst[i] = src[i];   // 2016
    }
    const int P[NJ] = {0,0,0,0,1,2,3,4,5,6,7,8,9,9,9,12,13,14,16,17,18,19};
    float* s_LD = reinterpret_cast<float*>(s_LD4);
    for (int i = tid; i < NJ*3; i += NT) {
        int j = i/3, c = i - j*3;
        float v = J_template[i];
        if (j) v -= J_template[P[j]*3 + c];
        s_LT[i] = v;
        s_LD[i*12 + 10] = 0.0f;
        s_LD[i*12 + 11] = 0.0f;
    }
    for (int i = tid; i < NJ*30; i += NT) {
        int jc = i/10, k = i - jc*10;
        int j = jc/3,  c = jc - j*3;
        float v = J_shapedirs[i];
        if (j) v -= J_shapedirs[(P[j]*3 + c)*10 + k];
        s_LD[jc*12 + k] = v;
    }
    __syncthreads();

    // ---- phase 2: body_pose LDS -> registers (stride-63 scalar reads, 2-way max) ----
    float aa[63];
    #pragma unroll
    for (int k = 0; k < 63; ++k) aa[k] = s_buf[tid*63 + k];
    __syncthreads();

    // ---- phase 3: stage betas / global_orient / transl into the same buffer ----
    {
        const float4* src = reinterpret_cast<const float4*>(betas + s0*10);
        float4* dst = reinterpret_cast<float4*>(s_buf);
        for (int i = tid; i < NT*10/4; i += NT) dst[i] = src[i];   // 320
    }
    {
        const float4* src = reinterpret_cast<const float4*>(global_orient + s0*3);
        float4* dst = reinterpret_cast<float4*>(s_buf + NT*10);
        if (tid < NT*3/4) dst[tid] = src[tid];                     // 96
    }
    {
        const float4* src = reinterpret_cast<const float4*>(transl + s0*3);
        float4* dst = reinterpret_cast<float4*>(s_buf + NT*13);
        if (tid < NT*3/4) dst[tid] = src[tid];                     // 96
    }
    __syncthreads();

    // ---- phase 4: betas/go/tr -> registers ----
    float bt[10];
    #pragma unroll
    for (int k = 0; k < 10; ++k) bt[k] = s_buf[tid*10 + k];
    const float gox = s_buf[NT*10 + tid*3 + 0];
    const float goy = s_buf[NT*10 + tid*3 + 1];
    const float goz = s_buf[NT*10 + tid*3 + 2];
    const float trx = s_buf[NT*13 + tid*3 + 0];
    const float try_ = s_buf[NT*13 + tid*3 + 1];
    const float trz = s_buf[NT*13 + tid*3 + 2];
    __syncthreads();

    // ---- phase 5: FK fully in registers; per-joint t written to s_buf[tid*66 + ...] ----
    float* s_o = &s_buf[tid*66];

    X9 g0;
    rodrigues(gox, goy, goz, g0.r);
    {
        float lt0[3];
        local_pos(0, bt, s_LT, s_LD4, lt0);
        g0.t[0] = lt0[0] + trx;
        g0.t[1] = lt0[1] + try_;
        g0.t[2] = lt0[2] + trz;
        s_o[0] = g0.t[0]; s_o[1] = g0.t[1]; s_o[2] = g0.t[2];
    }

    X9 g;
    // chain A: 0 -> 1 -> 4 -> 7 -> 10
    g = step<1 >(g0, aa, bt, s_LT, s_LD4, s_o);
    g = step<4 >(g,  aa, bt, s_LT, s_LD4, s_o);
    g = step<7 >(g,  aa, bt, s_LT, s_LD4, s_o);
    g = step<10>(g,  aa, bt, s_LT, s_LD4, s_o);
    // chain B: 0 -> 2 -> 5 -> 8 -> 11
    g = step<2 >(g0, aa, bt, s_LT, s_LD4, s_o);
    g = step<5 >(g,  aa, bt, s_LT, s_LD4, s_o);
    g = step<8 >(g,  aa, bt, s_LT, s_LD4, s_o);
    g = step<11>(g,  aa, bt, s_LT, s_LD4, s_o);
    // chain C: 0 -> 3 -> 6 -> 9
    g = step<3 >(g0, aa, bt, s_LT, s_LD4, s_o);
    g = step<6 >(g,  aa, bt, s_LT, s_LD4, s_o);
    X9 g9 = step<9>(g, aa, bt, s_LT, s_LD4, s_o);
    // chain D: 9 -> 12 -> 15
    g = step<12>(g9, aa, bt, s_LT, s_LD4, s_o);
    g = step<15>(g,  aa, bt, s_LT, s_LD4, s_o);
    // chain E: 9 -> 13 -> 16 -> 18 -> 20
    g = step<13>(g9, aa, bt, s_LT, s_LD4, s_o);
    g = step<16>(g,  aa, bt, s_LT, s_LD4, s_o);
    g = step<18>(g,  aa, bt, s_LT, s_LD4, s_o);
    g = step<20>(g,  aa, bt, s_LT, s_LD4, s_o);
    // chain F: 9 -> 14 -> 17 -> 19 -> 21
    g = step<14>(g9, aa, bt, s_LT, s_LD4, s_o);
    g = step<17>(g,  aa, bt, s_LT, s_LD4, s_o);
    g = step<19>(g,  aa, bt, s_LT, s_LD4, s_o);
    g = step<21>(g,  aa, bt, s_LT, s_LD4, s_o);

    __syncthreads();

    // ---- phase 6: pure float4 copy LDS -> global (conflict-free b128, coalesced) ----
    {
        const float4* src = reinterpret_cast<const float4*>(s_buf);
        float4* dst = reinterpret_cast<float4*>(out + s0 * (NJ*3));
        for (int i = tid; i < NT*NJ*3/4; i += NT) dst[i] = src[i];   // 2112
    }
}

extern "C" void kernel_launch(void* const* d_in, const int* in_sizes, int n_in,
                              void* d_out, int out_size, void* d_ws, size_t ws_size,
                              hipStream_t stream) {
    const float* body_pose     = (const float*)d_in[0];
    const float* betas         = (const float*)d_in[1];
    const float* global_orient = (const float*)d_in[2];
    const float* transl        = (const float*)d_in[3];
    const float* J_template    = (const float*)d_in[4];
    const float* J_shapedirs   = (const float*)d_in[5];
    float* out = (float*)d_out;

    const int S = in_sizes[0] / 63;        // B*L = 131072 (divisible by NT)
    const int blocks = S / NT;

    hipLaunchKernelGGL(fk_joints_kernel, dim3(blocks), dim3(NT), 0, stream,
                       body_pose, betas, global_orient, transl,
                       J_template, J_shapedirs, out);
}